// Round 3
// baseline (256.997 us; speedup 1.0000x reference)
//
#include <hip/hip_runtime.h>

typedef __bf16    bf16x8 __attribute__((ext_vector_type(8)));
typedef __bf16    bf16x4 __attribute__((ext_vector_type(4)));
typedef float     f32x4  __attribute__((ext_vector_type(4)));

#define BM 128
#define BN 128
#define BK 64

// async global->LDS, 16B per lane. LDS dest must be wave-uniform base + lane*16.
__device__ __forceinline__ void gload_lds16(const __bf16* g, __bf16* l) {
  __builtin_amdgcn_global_load_lds(
      (const __attribute__((address_space(1))) void*)g,
      (__attribute__((address_space(3))) void*)l,
      16, 0, 0);
}

// One launch converts x (8192 blocks) + Wq/Wk/Wv (3072 blocks) to bf16.
// Block 0 additionally zero-inits the row-sum accumulator.
__global__ void cvt_all(const float* __restrict__ x, const float* __restrict__ Wq,
                        const float* __restrict__ Wk, const float* __restrict__ Wv,
                        __bf16* __restrict__ xb, __bf16* __restrict__ Wqk,
                        __bf16* __restrict__ Wvb, float* __restrict__ lsum) {
  int b = blockIdx.x;
  if (b == 0) {
    for (int j = threadIdx.x; j < 8192; j += 256) lsum[j] = 0.f;
  }
  const float* src;
  __bf16* dst;
  int i;
  if (b < 8192) {
    src = x; dst = xb; i = b * 256 + threadIdx.x;
  } else {
    b -= 8192;
    const int mat = b >> 10;
    i = (b & 1023) * 256 + threadIdx.x;
    src = (mat == 0) ? Wq : (mat == 1) ? Wk : Wv;
    dst = (mat == 0) ? Wqk : (mat == 1) ? (Wqk + 1048576) : Wvb;
  }
  float4 v = ((const float4*)src)[i];
  bf16x4 o;
  o[0] = (__bf16)v.x; o[1] = (__bf16)v.y; o[2] = (__bf16)v.z; o[3] = (__bf16)v.w;
  ((bf16x4*)dst)[i] = o;
}

// ============================================================================
// 256x256 8-phase GEMM (m201 template) — round-3 status: used for QK ONLY.
// Round-2 A/B evidence: conflict-free (SQ_LDS_BANK_CONFLICT 0) but scores
// regressed on this structure (51.5->69us profiled) while the graph total
// improved 8.3us — attributed to QK. Scores reverted to the 128^2 kernel.
// Swizzle: LDS dest linear; rows 64B; cg = quad^((R>>1)&3) -> (R&1,cg)
// bijective over 8 rows -> 32 banks covered, 2 lanes/bank (free, m136).
// Source side: g = (chunk&3) ^ ((row>>1)&3) (both-sides rule #21).
// ============================================================================
template<int MODE>
__global__ __launch_bounds__(512, 2)
void gemm256(const __bf16* __restrict__ A, const __bf16* __restrict__ B,
             int lda, int ldb, int ldc, int K,
             long sA, long sB, long sC,
             const float* __restrict__ bias0, const float* __restrict__ bias1,
             float* __restrict__ lsum,
             __bf16* __restrict__ out0, __bf16* __restrict__ out1)
{
  // bijective XCD-chunked swizzle (nwg % 8 == 0)
  const int nwg = gridDim.x * gridDim.y * gridDim.z;
  int lin = blockIdx.x + gridDim.x * (blockIdx.y + gridDim.y * blockIdx.z);
  lin = (lin & 7) * (nwg >> 3) + (lin >> 3);
  const int bx = lin % gridDim.x;
  const int rest = lin / gridDim.x;
  const int by = rest % gridDim.y;
  const int bz = rest / gridDim.y;

  A += (long)bz * sA;
  B += (long)bz * sB;

  const int tid  = threadIdx.x;
  const int wave = tid >> 6;
  const int lane = tid & 63;
  const int quad = lane >> 4;
  const int l15  = lane & 15;
  const int bm0  = bx * 256;
  const int bn0  = by * 256;
  const int wm   = (wave >> 2) * 128;   // 2 M-waves
  const int wn   = (wave & 3) * 64;     // 4 N-waves

  __shared__ __align__(16) __bf16 As[4 * 8192];   // 4 slots x [256][32] = 64 KB
  __shared__ __align__(16) __bf16 Bs[4 * 8192];   // 64 KB

  f32x4 acc[8][4];
#pragma unroll
  for (int i = 0; i < 8; ++i)
#pragma unroll
    for (int j = 0; j < 4; ++j)
      acc[i][j] = (f32x4){0.f, 0.f, 0.f, 0.f};

  const int NH = K >> 5;                // number of 32-wide k-half slots

  const int r0 = tid >> 2;
  const int g0 = (tid & 3) ^ ((r0 >> 1) & 3);
  const __bf16* A0 = A + (size_t)(bm0 + r0) * lda + g0 * 8;
  const __bf16* A1 = A + (size_t)(bm0 + r0 + 128) * lda + g0 * 8;
  const __bf16* B0 = B + (size_t)(bn0 + r0) * ldb + g0 * 8;
  const __bf16* B1 = B + (size_t)(bn0 + r0 + 128) * ldb + g0 * 8;

  auto stageU = [&](int u) {            // unit u: slot u>>1, matrix = u&1
    const int s = u >> 1;
    if (s < NH) {
      if (u & 1) {
        __bf16* d = &Bs[(s & 3) * 8192 + tid * 8];
        gload_lds16(B0 + s * 32, d);
        gload_lds16(B1 + s * 32, d + 4096);
      } else {
        __bf16* d = &As[(s & 3) * 8192 + tid * 8];
        gload_lds16(A0 + s * 32, d);
        gload_lds16(A1 + s * 32, d + 4096);
      }
    }
  };

  // Fragment reads: row R -> R*32 + (quad^((R>>1)&3))*8; (R>>1)&3 == (l15>>1)&3.
  const int gq   = (quad ^ ((l15 >> 1) & 3)) * 8;
  const int aoff = (wm + l15) * 32 + gq;
  const int boff = (wn + l15) * 32 + gq;

  // ---- prologue: slots 0,1 staged + 3 units of slots 2,3 in flight ----
  stageU(0); stageU(1); stageU(2); stageU(3);
  asm volatile("s_waitcnt vmcnt(4)" ::: "memory");
  stageU(4); stageU(5); stageU(6);
  asm volatile("s_waitcnt vmcnt(6)" ::: "memory");
  __builtin_amdgcn_s_barrier();
  __builtin_amdgcn_sched_barrier(0);

  for (int h = 0; h < NH; ++h) {
    const int P = (h & 3) * 8192;
    bf16x8 af[4], bfv[4];
    // ---- phase A: M-half 0 + all B-frags (8 ds_read_b128) ----
#pragma unroll
    for (int ni = 0; ni < 4; ++ni)
      bfv[ni] = *(const bf16x8*)&Bs[P + ni * 512 + boff];
#pragma unroll
    for (int mi = 0; mi < 4; ++mi)
      af[mi] = *(const bf16x8*)&As[P + mi * 512 + aoff];
    stageU(2 * h + 7);
    __builtin_amdgcn_s_barrier();
    __builtin_amdgcn_s_setprio(1);
#pragma unroll
    for (int mi = 0; mi < 4; ++mi)
#pragma unroll
      for (int ni = 0; ni < 4; ++ni)
        acc[mi][ni] = __builtin_amdgcn_mfma_f32_16x16x32_bf16(
            af[mi], bfv[ni], acc[mi][ni], 0, 0, 0);
    __builtin_amdgcn_s_setprio(0);
    __builtin_amdgcn_s_barrier();
    // ---- phase B: M-half 1 (4 ds_read_b128, B-frags reused) ----
#pragma unroll
    for (int mi = 0; mi < 4; ++mi)
      af[mi] = *(const bf16x8*)&As[P + 2048 + mi * 512 + aoff];
    stageU(2 * h + 8);
    __builtin_amdgcn_s_barrier();
    __builtin_amdgcn_s_setprio(1);
#pragma unroll
    for (int mi = 0; mi < 4; ++mi)
#pragma unroll
      for (int ni = 0; ni < 4; ++ni)
        acc[mi + 4][ni] = __builtin_amdgcn_mfma_f32_16x16x32_bf16(
            af[mi], bfv[ni], acc[mi + 4][ni], 0, 0, 0);
    __builtin_amdgcn_s_setprio(0);
    if (h & 1) {                         // checkpoint: once per K-tile
      if (h + 4 < NH) asm volatile("s_waitcnt vmcnt(6)" ::: "memory");
      else            asm volatile("s_waitcnt vmcnt(0)" ::: "memory");
    }
    __builtin_amdgcn_s_barrier();
    if (h & 1) __builtin_amdgcn_sched_barrier(0);
  }

  // ---- epilogue. C/D layout: row = quad*4+r, col = lane&15 ----
  if (MODE == 2) {
    const long zc = (long)bz * sC;
#pragma unroll
    for (int mi = 0; mi < 8; ++mi) {
#pragma unroll
      for (int r = 0; r < 4; ++r) {
        const int gm = bm0 + wm + mi * 16 + quad * 4 + r;
        float part = 0.f;
#pragma unroll
        for (int ni = 0; ni < 4; ++ni) {
          const int gn = bn0 + wn + ni * 16 + l15;
          const __bf16 eb = (__bf16)__expf(acc[mi][ni][r] * 0.03125f);
          out0[zc + (size_t)gm * ldc + gn] = eb;
          part += (float)eb;
        }
        part += __shfl_xor(part, 1);
        part += __shfl_xor(part, 2);
        part += __shfl_xor(part, 4);
        part += __shfl_xor(part, 8);
        if (l15 == 0)
          atomicAdd(&lsum[bz * 2048 + gm], part);
      }
    }
  } else {  // MODE 0
#pragma unroll
    for (int mi = 0; mi < 8; ++mi) {
#pragma unroll
      for (int ni = 0; ni < 4; ++ni) {
        const int gn  = bn0 + wn + ni * 16 + l15;
        const int mat = gn >> 10;          // uniform per n-tile (256 | 1024)
        const int d   = gn & 1023;
        const float* bias = (mat == 0) ? bias0 : bias1;
        __bf16* dst = (mat == 0) ? out0 : out1;
#pragma unroll
        for (int r = 0; r < 4; ++r) {
          const int gm = bm0 + wm + mi * 16 + quad * 4 + r;
          dst[(size_t)gm * 1024 + d] = (__bf16)(acc[mi][ni][r] + bias[d]);
        }
      }
    }
  }
}

// ============================================================================
// 128x128 single-phase kernel (proven, m97 structure) — VT, scores, PV.
// ~2.3 blocks/CU resident: epilogue/prologue overlap across blocks, which the
// 1-block/CU 256^2 kernel cannot do — why scores runs better here (round-2).
// ============================================================================
template<int MODE>
__global__ __launch_bounds__(256, 2)
void gemm_bt(const __bf16* __restrict__ A, const __bf16* __restrict__ B,
             float* __restrict__ C,
             int lda, int ldb, int ldc, int K,
             long sA, long sB, long sC,
             const float* __restrict__ bias0, const float* __restrict__ bias1,
             float* __restrict__ lsum,
             __bf16* __restrict__ out0, __bf16* __restrict__ out1)
{
  A += (long)blockIdx.z * sA;
  B += (long)blockIdx.z * sB;

  const int tid  = threadIdx.x;
  const int wave = tid >> 6;
  const int lane = tid & 63;
  const int quad = lane >> 4;
  const int l15  = lane & 15;
  const int bm0  = blockIdx.x * BM;
  const int bn0  = blockIdx.y * BN;
  const int wm   = (wave >> 1) * 64;
  const int wn   = (wave & 1) * 64;

  __shared__ __align__(16) __bf16 As[BM * BK];   // 16 KB
  __shared__ __align__(16) __bf16 Bs[BN * BK];   // 16 KB

  f32x4 acc[4][4];
#pragma unroll
  for (int i = 0; i < 4; ++i)
#pragma unroll
    for (int j = 0; j < 4; ++j)
      acc[i][j] = (f32x4){0.f, 0.f, 0.f, 0.f};

  const __bf16* Ag[4];
  const __bf16* Bg[4];
#pragma unroll
  for (int c = 0; c < 4; ++c) {
    const int r  = c * 32 + (tid >> 3);
    const int g  = (tid & 7) ^ (r & 7);
    Ag[c] = A + (size_t)(bm0 + r) * lda + g * 8;
    Bg[c] = B + (size_t)(bn0 + r) * ldb + g * 8;
  }

  for (int k0 = 0; k0 < K; k0 += BK) {
#pragma unroll
    for (int c = 0; c < 4; ++c) {
      gload_lds16(Ag[c] + k0, &As[c * 2048 + tid * 8]);
      gload_lds16(Bg[c] + k0, &Bs[c * 2048 + tid * 8]);
    }
    __syncthreads();

#pragma unroll
    for (int kk = 0; kk < 2; ++kk) {
      bf16x8 af[4], bfv[4];
#pragma unroll
      for (int i = 0; i < 4; ++i) {
        const int R = wm + i * 16 + l15;
        af[i] = *(const bf16x8*)&As[R * BK + (((kk * 4 + quad) ^ (R & 7)) * 8)];
      }
#pragma unroll
      for (int i = 0; i < 4; ++i) {
        const int R = wn + i * 16 + l15;
        bfv[i] = *(const bf16x8*)&Bs[R * BK + (((kk * 4 + quad) ^ (R & 7)) * 8)];
      }
#pragma unroll
      for (int mi = 0; mi < 4; ++mi)
#pragma unroll
        for (int ni = 0; ni < 4; ++ni)
          acc[mi][ni] = __builtin_amdgcn_mfma_f32_16x16x32_bf16(
              af[mi], bfv[ni], acc[mi][ni], 0, 0, 0);
    }
    __syncthreads();
  }

  // Epilogue. C/D layout (verified m89/m91): row m = quad*4+r, col n = lane&15.
  if (MODE == 2) {
    // scores: w = exp(v/32) -> bf16; row sums into lsum via shfl+atomic.
#pragma unroll
    for (int mi = 0; mi < 4; ++mi) {
#pragma unroll
      for (int r = 0; r < 4; ++r) {
        const int gm = bm0 + wm + mi * 16 + quad * 4 + r;
        float part = 0.f;
#pragma unroll
        for (int ni = 0; ni < 4; ++ni) {
          const int gn = bn0 + wn + ni * 16 + l15;
          const __bf16 eb = (__bf16)__expf(acc[mi][ni][r] * 0.03125f);
          out0[(long)blockIdx.z * sC + (size_t)gm * ldc + gn] = eb;
          part += (float)eb;  // sum the rounded values PV will actually read
        }
        part += __shfl_xor(part, 1);
        part += __shfl_xor(part, 2);
        part += __shfl_xor(part, 4);
        part += __shfl_xor(part, 8);
        if (l15 == 0)
          atomicAdd(&lsum[blockIdx.z * 2048 + gm], part);
      }
    }
  } else if (MODE == 3) {
    // PV: normalize by row sum while storing fp32.
#pragma unroll
    for (int mi = 0; mi < 4; ++mi) {
#pragma unroll
      for (int r = 0; r < 4; ++r) {
        const int gm = bm0 + wm + mi * 16 + quad * 4 + r;
        const float rv = 1.0f / lsum[blockIdx.z * 2048 + gm];
#pragma unroll
        for (int ni = 0; ni < 4; ++ni) {
          const int gn = bn0 + wn + ni * 16 + l15;
          C[(long)blockIdx.z * sC + (size_t)gm * ldc + gn] = acc[mi][ni][r] * rv;
        }
      }
    }
  } else {  // MODE 1 (VT)
#pragma unroll
    for (int mi = 0; mi < 4; ++mi) {
#pragma unroll
      for (int ni = 0; ni < 4; ++ni) {
        const int gn = bn0 + wn + ni * 16 + l15;
#pragma unroll
        for (int r = 0; r < 4; ++r) {
          const int gm = bm0 + wm + mi * 16 + quad * 4 + r;
          const int b = gn >> 11, s = gn & 2047;
          out0[(size_t)b * (1024 * 2048) + (size_t)gm * 2048 + s] =
              (__bf16)(acc[mi][ni][r] + bias0[gm]);
        }
      }
    }
  }
}

extern "C" void kernel_launch(void* const* d_in, const int* in_sizes, int n_in,
                              void* d_out, int out_size, void* d_ws, size_t ws_size,
                              hipStream_t stream) {
  const float* x  = (const float*)d_in[0];
  const float* Wq = (const float*)d_in[1];
  const float* bq = (const float*)d_in[2];
  const float* Wk = (const float*)d_in[3];
  const float* bk = (const float*)d_in[4];
  const float* Wv = (const float*)d_in[5];
  const float* bv = (const float*)d_in[6];
  float* out = (float*)d_out;

  // ws layout:
  //  [0,16M)    Q    bf16 [8192][1024]
  //  [16,32M)   K    bf16 [8192][1024]
  //  [32,48M)   Vt   bf16 [4][1024][2048]
  //  [48,64M)   xb   bf16 (projection phase only)
  //  [64,68M)   Wqk  bf16 [2048][1024] (projection phase only)
  //  [68,70M)   Wvb  bf16 [1024][1024] (projection phase only)
  //  [48,80M)   Sc   bf16 [4][2048][2048] exp-weights (aliases xb/Wqk/Wvb)
  //  [110M,+32K) lsum fp32 [8192] row sums (zeroed by cvt_all block 0)
  char* ws = (char*)d_ws;
  __bf16* Q    = (__bf16*)(ws);
  __bf16* Kb   = (__bf16*)(ws + (16ull << 20));
  __bf16* Vt   = (__bf16*)(ws + (32ull << 20));
  __bf16* xb   = (__bf16*)(ws + (48ull << 20));
  __bf16* Wqk  = (__bf16*)(ws + (64ull << 20));
  __bf16* Wvb  = (__bf16*)(ws + (68ull << 20));
  __bf16* Sc   = (__bf16*)(ws + (48ull << 20));
  float*  lsum = (float*)(ws + (110ull << 20));

  // fp32 -> bf16 (+ lsum zero-init), one launch
  cvt_all<<<11264, dim3(256), 0, stream>>>(x, Wq, Wk, Wv, xb, Wqk, Wvb, lsum);

  // QK: [8192,1024] @ [2048,1024]^T -> Q, K (bf16, +bias)   [256^2 8-phase]
  gemm256<0><<<dim3(32, 8, 1), dim3(512), 0, stream>>>(
      xb, Wqk, 1024, 1024, 1024, 1024,
      0L, 0L, 0L, bq, bk, nullptr, Q, Kb);

  // VT: Wv[1024,1024] @ xb[8192,1024]^T -> Vt[b][d][s] (bf16, +bias[d])
  gemm_bt<1><<<dim3(8, 64, 1), dim3(256), 0, stream>>>(
      Wvb, xb, nullptr, 1024, 1024, 0, 1024,
      0L, 0L, 0L, bv, nullptr, nullptr, Vt, nullptr);

  // scores: per batch Q[2048,1024] @ K[2048,1024]^T -> bf16 exp-weights + lsum
  // [reverted to 128^2: regressed on the 256^2 8-phase structure, round-2]
  gemm_bt<2><<<dim3(16, 16, 4), dim3(256), 0, stream>>>(
      Q, Kb, nullptr, 1024, 1024, 2048, 1024,
      2048L * 1024, 2048L * 1024, 2048L * 2048,
      nullptr, nullptr, lsum, Sc, nullptr);

  // PV: per batch Sc[2048,2048](bf16) @ Vt[1024,2048]^T -> out fp32, /lsum
  gemm_bt<3><<<dim3(16, 8, 4), dim3(256), 0, stream>>>(
      Sc, Vt, out, 2048, 2048, 1024, 2048,
      2048L * 2048, 1024L * 2048, 2048L * 1024,
      nullptr, nullptr, lsum, nullptr, nullptr);
}